// Round 4
// baseline (662.409 us; speedup 1.0000x reference)
//
#include <hip/hip_runtime.h>

#define B_DIM 32
#define N_DIM 16384
#define D 128
#define SUM_CHUNKS 16         // chunks per batch (PROVEN ws footprint: 278 KB)

typedef __attribute__((ext_vector_type(8))) short short8;     // 8 bf16 = 4 VGPRs
typedef __attribute__((ext_vector_type(16))) float floatx16;  // 32x32 MFMA accumulator

__device__ __forceinline__ short f2bf(float f) {
    // round-to-nearest-even fp32 -> bf16 bits
    unsigned u = __builtin_bit_cast(unsigned, f);
    u = (u + 0x7FFFu + ((u >> 16) & 1u)) >> 16;
    return (short)u;
}

// ---------------------------------------------------------------------------
// Kernel 1: per-chunk column sums of x.  grid = B*SUM_CHUNKS blocks x 256 thr.
// Per-wave loads are 2 rows x 512 B fully coalesced — already near peak.
// ---------------------------------------------------------------------------
__global__ __launch_bounds__(256) void colsum_kernel(const float* __restrict__ x,
                                                     float* __restrict__ part) {
    const int CHUNK = N_DIM / SUM_CHUNKS;   // 1024 rows
    int b = blockIdx.x / SUM_CHUNKS;
    int chunk = blockIdx.x % SUM_CHUNKS;
    const float4* xp = (const float4*)(x + ((size_t)b * N_DIM + (size_t)chunk * CHUNK) * D);
    int cg = threadIdx.x & 31;   // column group: 4 consecutive floats
    int rl = threadIdx.x >> 5;   // row lane 0..7
    float4 acc = make_float4(0.f, 0.f, 0.f, 0.f);
    #pragma unroll 4
    for (int r = rl; r < CHUNK; r += 8) {
        float4 v = xp[(size_t)r * 32 + cg];
        acc.x += v.x; acc.y += v.y; acc.z += v.z; acc.w += v.w;
    }
    __shared__ float4 red[256];
    red[threadIdx.x] = acc;
    __syncthreads();
    if (threadIdx.x < 32) {
        float4 s = red[threadIdx.x];
        #pragma unroll
        for (int i = 1; i < 8; i++) {
            float4 v = red[threadIdx.x + 32 * i];
            s.x += v.x; s.y += v.y; s.z += v.z; s.w += v.w;
        }
        float4* dst = (float4*)(part + (size_t)blockIdx.x * D);
        dst[cg] = s;
    }
}

// ---------------------------------------------------------------------------
// Kernel 2: pooled_bias[b][e] = bias[e] + sum_d xsum[b][d] * w2[d][e]
// ---------------------------------------------------------------------------
__global__ __launch_bounds__(128) void pooled_kernel(const float* __restrict__ part,
                                                     const float* __restrict__ w2,
                                                     const float* __restrict__ bias,
                                                     float* __restrict__ pooled) {
    int b = blockIdx.x;
    int e = threadIdx.x;
    __shared__ float xs[D];
    float s = 0.f;
    #pragma unroll
    for (int c = 0; c < SUM_CHUNKS; c++)
        s += part[((size_t)b * SUM_CHUNKS + c) * D + e];
    xs[e] = s;
    __syncthreads();
    float acc = bias[e];
    #pragma unroll 8
    for (int d0 = 0; d0 < D; d0++) acc += xs[d0] * w2[d0 * D + e];
    pooled[b * D + e] = acc;
}

// ---------------------------------------------------------------------------
// Kernel 3: out[b,n,e] = (x @ w1)[b,n,e] + pooled_bias[b,e]
// mfma_f32_32x32x16_bf16, NON-swapped (A = x rows, B = w1 cols).
// C layout (HW-verified m74/m101): col = lane&31, row = (g&3)+8*(g>>2)+4*(lane>>5).
// => each scalar store instruction writes TWO complete 128 B lines
//    (lanes 0-31: 32 consecutive cols of one row; lanes 32-63: row+4).
//    No partial-line writes -> no write-allocate RMW fetch (round-3 pathology:
//    FETCH 495 MB vs 268 ideal came from 64B-granular store instructions).
// w1 staged in LDS in EXACT fragment order w1s[ks][et][lane][8] so every
// ds_read_b128 is lane-linear = bank-conflict-free.
// pooled folded into acc-init (per et-tile, all 16 regs share one column).
// LDS = 32.5 KB -> 4 blocks/CU at launch_bounds(256,4); grid = 4 x 256 CUs.
// ---------------------------------------------------------------------------
__global__ __launch_bounds__(256, 4) void gemm_kernel(const float* __restrict__ x,
                                                      const float* __restrict__ w1,
                                                      const float* __restrict__ pooled,
                                                      float* __restrict__ out) {
    __shared__ __align__(16) short w1s[8 * 4 * 64 * 8];  // [ks][et][lane][j] = 32 KB
    __shared__ float pbl[D];

    const int CHUNKS = 32;                   // 512 rows per block
    int b     = blockIdx.x / CHUNKS;
    int chunk = blockIdx.x % CHUNKS;

    // Stage w1 into fragment-linear order. chunk index c -> (ks, et, lane):
    //   frag[j] = w1[k0 + j][e],  k0 = ks*16 + (lane>>5)*8,  e = et*32 + (lane&31)
    // 8 strided scalar reads per chunk; w1 is 64 KB and L2/L3-hot — one-time cost.
    for (int c = threadIdx.x; c < 2048; c += 256) {
        int l  = c & 63;
        int et = (c >> 6) & 3;
        int ks = c >> 8;
        int e  = et * 32 + (l & 31);
        int k0 = ks * 16 + (l >> 5) * 8;
        short8 frag;
        #pragma unroll
        for (int j = 0; j < 8; j++) frag[j] = f2bf(w1[(size_t)(k0 + j) * D + e]);
        *(short8*)&w1s[(size_t)c * 8] = frag;
    }
    if (threadIdx.x < D) pbl[threadIdx.x] = pooled[b * D + threadIdx.x];
    __syncthreads();

    int wave = threadIdx.x >> 6;
    int lane = threadIdx.x & 63;
    int col  = lane & 31;                    // A row (x row within tile) AND C col
    int hi   = lane >> 5;                    // k-subchunk selector / C row offset

    size_t rowbase = (size_t)b * N_DIM + (size_t)chunk * 512 + (size_t)wave * 128;

    // pooled_bias per et-tile for this lane's output column (loop-invariant)
    float pb[4];
    #pragma unroll
    for (int et = 0; et < 4; et++) pb[et] = pbl[et * 32 + col];

    for (int t = 0; t < 4; t++) {            // 4 tiles of 32 rows = 128 rows/wave
        // lane's x row and k-chunk base: k = hi*8 + ks*16 + j (32 B contiguous/ks)
        const float* xrow = x + (rowbase + (size_t)t * 32 + col) * D + hi * 8;

        floatx16 acc[4];
        #pragma unroll
        for (int et = 0; et < 4; et++) {
            #pragma unroll
            for (int g = 0; g < 16; g++) acc[et][g] = pb[et];
        }

        #pragma unroll
        for (int ks = 0; ks < 8; ks++) {
            float4 a0 = *(const float4*)(xrow + ks * 16);
            float4 a1 = *(const float4*)(xrow + ks * 16 + 4);
            short8 af;
            af[0] = f2bf(a0.x); af[1] = f2bf(a0.y); af[2] = f2bf(a0.z); af[3] = f2bf(a0.w);
            af[4] = f2bf(a1.x); af[5] = f2bf(a1.y); af[6] = f2bf(a1.z); af[7] = f2bf(a1.w);
            #pragma unroll
            for (int et = 0; et < 4; et++) {
                short8 bf = *(const short8*)&w1s[((ks * 4 + et) * 64 + lane) * 8];
                acc[et] = __builtin_amdgcn_mfma_f32_32x32x16_bf16(af, bf, acc[et], 0, 0, 0);
            }
        }

        // Epilogue: store instruction (et,g) writes 2 full 128B lines.
        float* obase = out + (rowbase + (size_t)t * 32) * D;
        #pragma unroll
        for (int et = 0; et < 4; et++) {
            #pragma unroll
            for (int g = 0; g < 16; g++) {
                int i = (g & 3) + 8 * (g >> 2) + 4 * hi;   // C row
                obase[(size_t)i * D + et * 32 + col] = acc[et][g];
            }
        }
    }
}

extern "C" void kernel_launch(void* const* d_in, const int* in_sizes, int n_in,
                              void* d_out, int out_size, void* d_ws, size_t ws_size,
                              hipStream_t stream) {
    const float* x    = (const float*)d_in[0];
    const float* w1   = (const float*)d_in[1];
    const float* w2   = (const float*)d_in[2];
    const float* bias = (const float*)d_in[3];
    float* out = (float*)d_out;

    // ws layout: [0, B*SUM_CHUNKS*D) partial column sums, then [.., +B*D) pooled_bias
    // footprint = 32*16*128 + 32*128 floats = 278 KB (proven)
    float* part   = (float*)d_ws;
    float* pooled = part + (size_t)B_DIM * SUM_CHUNKS * D;

    colsum_kernel<<<B_DIM * SUM_CHUNKS, 256, 0, stream>>>(x, part);
    pooled_kernel<<<B_DIM, 128, 0, stream>>>(part, w2, bias, pooled);
    gemm_kernel<<<B_DIM * 32, 256, 0, stream>>>(x, w1, pooled, out);
}